// Round 8
// baseline (3538.059 us; speedup 1.0000x reference)
//
#include <hip/hip_runtime.h>
#include <hip/hip_bf16.h>

#define NN 100000
#define NE 1600000
#define RB 128                        // rows per destination block
#define RBK ((NN + RB - 1) / RB)      // 782 row-blocks
#define CAP 2560                      // int2 slots per block region (mean 2047, +11 sigma)
#define CHUNK 4096                    // edges per phase-A workgroup
#define CB 98                         // col buckets (col >> 10)

typedef _Float16 f16;
typedef f16 f16x8 __attribute__((ext_vector_type(8)));
typedef float f32x4 __attribute__((ext_vector_type(4)));

// ---------------- adjacency build ----------------

__global__ void zero_i32(int* __restrict__ p, int n) {
    int i = blockIdx.x * blockDim.x + threadIdx.x;
    if (i < n) p[i] = 0;
}

// Phase A: counting-sort each 4096-edge chunk by row-block in LDS, stream grouped
// runs contiguously into per-block regions (contiguous global writes only).
__global__ __launch_bounds__(256) void bin_edges(const int* __restrict__ row,
                                                 const int* __restrict__ col,
                                                 int* __restrict__ bcursor,
                                                 int2* __restrict__ binned) {
    __shared__ int  bcnt[RBK];
    __shared__ int  bbase[RBK];
    __shared__ int  lstart[RBK];
    __shared__ int  bcur[RBK];
    __shared__ int2 stage[CHUNK];
    int tid = threadIdx.x;
    int e0 = blockIdx.x * CHUNK;
    int emax = min(CHUNK, NE - e0);

    for (int b = tid; b < RBK; b += 256) bcnt[b] = 0;
    __syncthreads();
    for (int i = tid; i < emax; i += 256)
        atomicAdd(&bcnt[row[e0 + i] >> 7], 1);
    __syncthreads();
    if (tid == 0) {
        int s = 0;
        for (int b = 0; b < RBK; ++b) { lstart[b] = s; s += bcnt[b]; }
    }
    __syncthreads();
    for (int b = tid; b < RBK; b += 256) {
        bcur[b]  = lstart[b];
        bbase[b] = bcnt[b] ? atomicAdd(&bcursor[b], bcnt[b]) : 0;
    }
    __syncthreads();
    for (int i = tid; i < emax; i += 256) {
        int r = row[e0 + i], c = col[e0 + i];
        int pos = atomicAdd(&bcur[r >> 7], 1);
        stage[pos] = make_int2(r, c);
    }
    __syncthreads();
    for (int i = tid; i < emax; i += 256) {
        int2 rc = stage[i];
        int b = rc.x >> 7;
        binned[(size_t)b * CAP + bbase[b] + (i - lstart[b])] = rc;
    }
}

// Phase B: per row-block, sort edges by col-bucket (col>>10) in LDS, pack to
// (localrow<<17 | col) words written IN PLACE over the block's own binned
// region; compute degrees -> dinv. No CSR needed.
__global__ __launch_bounds__(256) void build_blocks(const int* __restrict__ bcount,
                                                    int2* __restrict__ binned,
                                                    float* __restrict__ dinv) {
    __shared__ int cstart[CB];
    __shared__ int ccur[CB];
    __shared__ int rdeg[RB];
    __shared__ int ebuf[CAP];
    int tid = threadIdx.x;
    int b = blockIdx.x;
    int r0 = b * RB;
    int n = min(bcount[b], CAP);
    const int2* src = binned + (size_t)b * CAP;

    for (int i = tid; i < CB; i += 256) ccur[i] = 0;
    for (int i = tid; i < RB; i += 256) rdeg[i] = 0;
    __syncthreads();
    for (int i = tid; i < n; i += 256) {
        int2 rc = src[i];
        atomicAdd(&ccur[rc.y >> 10], 1);
        atomicAdd(&rdeg[rc.x - r0], 1);
    }
    __syncthreads();
    if (tid == 0) {
        int s = 0;
        for (int c = 0; c < CB; ++c) { cstart[c] = s; s += ccur[c]; }
    }
    __syncthreads();
    for (int i = tid; i < CB; i += 256) ccur[i] = cstart[i];
    __syncthreads();
    for (int i = tid; i < n; i += 256) {
        int2 rc = src[i];
        int pos = atomicAdd(&ccur[rc.y >> 10], 1);
        ebuf[pos] = ((rc.x - r0) << 17) | rc.y;
    }
    __syncthreads();
    int* eout = (int*)(binned + (size_t)b * CAP);   // own region only; safe after sync
    for (int i = tid; i < n; i += 256) eout[i] = ebuf[i];
    int r = r0 + tid;
    if (tid < RB && r < NN) dinv[r] = rsqrtf((float)(rdeg[tid] + 1));
}

// ---------------- MFMA f16 GEMM: T[N,F] = f16( dinv[r] * (A[N,128] @ W[128,F]) ) ----------------
template<int F, bool AFP32>
__global__ __launch_bounds__(256) void gemm_mfma(const void* __restrict__ Ain,
                                                 const float* __restrict__ W,
                                                 const float* __restrict__ dinv,
                                                 f16* __restrict__ T) {
    constexpr int PITCH = 136;
    __shared__ f16 Wt[F * PITCH];
    int tid = threadIdx.x;
    for (int e = tid; e < 128 * F; e += 256) {
        int k = e / F, n = e - k * F;
        Wt[n * PITCH + k] = (f16)W[e];
    }
    __syncthreads();

    int wave = tid >> 6;
    int lane = tid & 63;
    int m = lane & 15, q = lane >> 4;
    int r0 = blockIdx.x * 64 + wave * 16;
    int ra = min(r0 + m, NN - 1);

    constexpr int NT = F / 16;
    f32x4 acc[NT];
    #pragma unroll
    for (int t = 0; t < NT; ++t) acc[t] = (f32x4){0.f, 0.f, 0.f, 0.f};

    #pragma unroll
    for (int c = 0; c < 4; ++c) {            // K = 128 = 4 x 32
        f16x8 a;
        if (AFP32) {
            const float* Af = (const float*)Ain;
            const float4* p = (const float4*)&Af[(size_t)ra * 128 + c * 32 + q * 8];
            float4 lo = p[0], hi = p[1];
            a[0] = (f16)lo.x; a[1] = (f16)lo.y; a[2] = (f16)lo.z; a[3] = (f16)lo.w;
            a[4] = (f16)hi.x; a[5] = (f16)hi.y; a[6] = (f16)hi.z; a[7] = (f16)hi.w;
        } else {
            const f16* Ah = (const f16*)Ain;
            a = *(const f16x8*)&Ah[(size_t)ra * 128 + c * 32 + q * 8];
        }
        #pragma unroll
        for (int t = 0; t < NT; ++t) {
            f16x8 b = *(const f16x8*)&Wt[(t * 16 + m) * PITCH + c * 32 + q * 8];
            acc[t] = __builtin_amdgcn_mfma_f32_16x16x32_f16(a, b, acc[t], 0, 0, 0);
        }
    }

    int rows[4];
    float dv[4];
    #pragma unroll
    for (int i = 0; i < 4; ++i) {
        rows[i] = r0 + q * 4 + i;
        dv[i] = dinv[min(rows[i], NN - 1)];
    }
    #pragma unroll
    for (int t = 0; t < NT; ++t) {
        #pragma unroll
        for (int i = 0; i < 4; ++i) {
            if (rows[i] < NN) {
                T[(size_t)rows[i] * F + t * 16 + m] = (f16)(acc[t][i] * dv[i]);
            }
        }
    }
}

// ---------------- SpMM accumulate: destination-blocked, col-sorted edges ----------------
// WG owns 128 dest rows; fp32 accumulators in LDS. Edge list sorted by col-bucket:
// all WGs sweep T in ascending col order concurrently -> L2/L3-resident window.
// LDS address uses +lr feature rotation to break bank-conflict cosets.
// out[r] = dinv[r]*(acc[r] + T'[r]) + b ; T' is dinv-prescaled.
template<int F, bool RELU, bool OUTF16>
__global__ __launch_bounds__(512) void spmm_acc(const f16* __restrict__ T,
                                                const int2* __restrict__ binned,
                                                const int* __restrict__ bcount,
                                                const float* __restrict__ dinv,
                                                const float* __restrict__ bias,
                                                void* __restrict__ outv) {
    extern __shared__ float acc[];       // RB * F floats
    constexpr int LPR = F / 8;           // lanes per edge/row: 16 (F=128) or 8 (F=64)
    constexpr int NSLOT = 512 / LPR;     // concurrent edge slots: 32 or 64
    int tid  = threadIdx.x;
    int b    = blockIdx.x;
    int r0   = b * RB;
    int n    = min(bcount[b], CAP);
    const int* edges = (const int*)(binned + (size_t)b * CAP);
    const f16x8* Tv = (const f16x8*)T;

    for (int i = tid; i < RB * F; i += 512) acc[i] = 0.f;
    __syncthreads();

    int lane = tid % LPR;
    int slot = tid / LPR;
    for (int i = slot; i < n; i += NSLOT) {
        int w  = edges[i];
        int lr = w >> 17;
        int c  = w & 0x1FFFF;
        f16x8 v = Tv[(size_t)c * LPR + lane];
        int base = lr * F;
        int f0 = lane * 8;
        #pragma unroll
        for (int u = 0; u < 8; ++u) {
            atomicAdd(&acc[base + ((f0 + u + lr) & (F - 1))], (float)v[u]);
        }
    }
    __syncthreads();

    for (int idx = tid; idx < RB * LPR; idx += 512) {
        int row = idx / LPR, ln = idx % LPR;
        int r = r0 + row;
        if (r >= NN) continue;
        float dr = dinv[r];
        f16x8 self = Tv[(size_t)r * LPR + ln];
        int base = row * F, f0 = ln * 8;
        float o[8];
        #pragma unroll
        for (int u = 0; u < 8; ++u) {
            float a = acc[base + ((f0 + u + row) & (F - 1))];
            o[u] = fmaf(dr, a + (float)self[u], bias[f0 + u]);
            if (RELU) o[u] = fmaxf(o[u], 0.f);
        }
        if (OUTF16) {
            f16x8 h;
            #pragma unroll
            for (int u = 0; u < 8; ++u) h[u] = (f16)o[u];
            ((f16x8*)outv)[(size_t)r * LPR + ln] = h;
        } else {
            float* outF = (float*)outv;
            float4 lo = make_float4(o[0], o[1], o[2], o[3]);
            float4 hi = make_float4(o[4], o[5], o[6], o[7]);
            *(float4*)&outF[(size_t)r * F + f0]     = lo;
            *(float4*)&outF[(size_t)r * F + f0 + 4] = hi;
        }
    }
}

// ---------------- launch ----------------

extern "C" void kernel_launch(void* const* d_in, const int* in_sizes, int n_in,
                              void* d_out, int out_size, void* d_ws, size_t ws_size,
                              hipStream_t stream) {
    const float* x  = (const float*)d_in[0];
    const int*   ei = (const int*)d_in[1];
    const float* W0 = (const float*)d_in[2];
    const float* b0 = (const float*)d_in[3];
    const float* W1 = (const float*)d_in[4];
    const float* b1 = (const float*)d_in[5];
    const float* W2 = (const float*)d_in[6];
    const float* b2 = (const float*)d_in[7];
    float* out = (float*)d_out;

    const int* row = ei;
    const int* col = ei + NE;

    char* wsp = (char*)d_ws;
    auto alloc = [&](size_t bytes) {
        char* p = wsp;
        wsp += (bytes + 255) & ~(size_t)255;
        return p;
    };
    int*   bcursor = (int*)alloc((size_t)RBK * 4);
    int2*  binned  = (int2*)alloc((size_t)RBK * CAP * 8);   // 16.0 MB; reused as packed edges
    float* dinv    = (float*)alloc((size_t)NN * 4);
    f16*   Tbuf    = (f16*)alloc((size_t)NN * 128 * 2);
    f16*   Hbuf    = (f16*)alloc((size_t)NN * 128 * 2);

    // adjacency build: bin by row-block, then per-block col-sort + degrees
    zero_i32<<<(RBK + 255) / 256, 256, 0, stream>>>(bcursor, RBK);
    bin_edges<<<(NE + CHUNK - 1) / CHUNK, 256, 0, stream>>>(row, col, bcursor, binned);
    build_blocks<<<RBK, 256, 0, stream>>>(bcursor, binned, dinv);

    const int GB = (NN + 63) / 64;

    // layer 1
    gemm_mfma<128, true><<<GB, 256, 0, stream>>>(x, W0, dinv, Tbuf);
    spmm_acc<128, true, true><<<RBK, 512, RB * 128 * 4, stream>>>(Tbuf, binned, bcursor, dinv, b0, Hbuf);
    // layer 2
    gemm_mfma<128, false><<<GB, 256, 0, stream>>>(Hbuf, W1, dinv, Tbuf);
    spmm_acc<128, true, true><<<RBK, 512, RB * 128 * 4, stream>>>(Tbuf, binned, bcursor, dinv, b1, Hbuf);
    // layer 3 (no relu) -> fp32 d_out
    gemm_mfma<64, false><<<GB, 256, 0, stream>>>(Hbuf, W2, dinv, Tbuf);
    spmm_acc<64, false, false><<<RBK, 512, RB * 64 * 4, stream>>>(Tbuf, binned, bcursor, dinv, b2, out);
}

// Round 9
// 383.855 us; speedup vs baseline: 9.2172x; 9.2172x over previous
//
#include <hip/hip_runtime.h>
#include <hip/hip_bf16.h>

#define NN 100000
#define NE 1600000
#define BK 98               // row buckets: row >> 10, rows 0..99999 -> 0..97
#define CAP 18432           // slots per bucket region (mean 16384, sigma ~127)
#define CHUNK 8192          // edges per phase-A workgroup

typedef _Float16 f16;
typedef f16 f16x8 __attribute__((ext_vector_type(8)));
typedef float f32x4 __attribute__((ext_vector_type(4)));

// ---------------- adjacency build: two-phase binned CSR (R7, proven) ----------------

__global__ void zero_i32(int* __restrict__ p, int n) {
    int i = blockIdx.x * blockDim.x + threadIdx.x;
    if (i < n) p[i] = 0;
}

__global__ __launch_bounds__(256) void bin_edges(const int* __restrict__ row,
                                                 const int* __restrict__ col,
                                                 int* __restrict__ bcursor,
                                                 int2* __restrict__ binned) {
    __shared__ int  bcnt[BK];
    __shared__ int  bbase[BK];
    __shared__ int  lstart[BK + 1];
    __shared__ int  bcur[BK];
    __shared__ int2 stage[CHUNK];
    int tid = threadIdx.x;
    int e0 = blockIdx.x * CHUNK;
    int emax = min(CHUNK, NE - e0);

    if (tid < BK) bcnt[tid] = 0;
    __syncthreads();
    for (int i = tid; i < emax; i += 256)
        atomicAdd(&bcnt[row[e0 + i] >> 10], 1);
    __syncthreads();
    if (tid == 0) {
        int s = 0;
        for (int b = 0; b < BK; ++b) { lstart[b] = s; s += bcnt[b]; }
        lstart[BK] = s;
    }
    __syncthreads();
    if (tid < BK) {
        bcur[tid]  = lstart[tid];
        bbase[tid] = atomicAdd(&bcursor[tid], bcnt[tid]);
    }
    __syncthreads();
    for (int i = tid; i < emax; i += 256) {
        int r = row[e0 + i], c = col[e0 + i];
        int pos = atomicAdd(&bcur[r >> 10], 1);
        stage[pos] = make_int2(r, c);
    }
    __syncthreads();
    for (int i = tid; i < emax; i += 256) {
        int2 rc = stage[i];
        int b = rc.x >> 10;
        binned[(size_t)b * CAP + bbase[b] + (i - lstart[b])] = rc;
    }
}

__global__ __launch_bounds__(1024) void build_csr(const int* __restrict__ bcount,
                                                  const int2* __restrict__ binned,
                                                  int* __restrict__ offsets,
                                                  float* __restrict__ dinv,
                                                  int* __restrict__ csr_col) {
    __shared__ int cnt[1024];
    __shared__ int sc[1024];
    __shared__ int colbuf[CAP];
    __shared__ int mybase_s;
    int tid = threadIdx.x;
    int b = blockIdx.x;
    int r0 = b << 10;
    int nrows = min(1024, NN - r0);

    if (tid < BK) sc[tid] = bcount[tid];
    cnt[tid] = 0;
    __syncthreads();
    if (tid == 0) {
        int s = 0;
        for (int i = 0; i < b; ++i) s += sc[i];
        mybase_s = s;
    }
    int n = sc[b];
    __syncthreads();
    int mybase = mybase_s;
    const int2* src = binned + (size_t)b * CAP;

    for (int i = tid; i < n; i += 1024)
        atomicAdd(&cnt[src[i].x - r0], 1);
    __syncthreads();

    int v = cnt[tid];
    sc[tid] = v;
    __syncthreads();
    #pragma unroll
    for (int s = 1; s < 1024; s <<= 1) {
        int t = (tid >= s) ? sc[tid - s] : 0;
        __syncthreads();
        sc[tid] += t;
        __syncthreads();
    }
    int incl = sc[tid];
    if (tid < nrows) {
        offsets[r0 + tid + 1] = mybase + incl;
        dinv[r0 + tid] = rsqrtf((float)(v + 1));   // +1 self loop
    }
    if (b == 0 && tid == 0) offsets[0] = 0;

    cnt[tid] = incl - v;
    __syncthreads();
    for (int i = tid; i < n; i += 1024) {
        int2 rc = src[i];
        int pos = atomicAdd(&cnt[rc.x - r0], 1);
        colbuf[pos] = rc.y;
    }
    __syncthreads();
    for (int i = tid; i < n; i += 1024)
        csr_col[mybase + i] = colbuf[i];
}

// ---------------- MFMA f16 GEMM: T[N,F] = f16( dinv[r] * (A[N,128] @ W[128,F]) ) ----------------
template<int F, bool AFP32>
__global__ __launch_bounds__(256) void gemm_mfma(const void* __restrict__ Ain,
                                                 const float* __restrict__ W,
                                                 const float* __restrict__ dinv,
                                                 f16* __restrict__ T) {
    constexpr int PITCH = 136;
    __shared__ f16 Wt[F * PITCH];
    int tid = threadIdx.x;
    for (int e = tid; e < 128 * F; e += 256) {
        int k = e / F, n = e - k * F;
        Wt[n * PITCH + k] = (f16)W[e];
    }
    __syncthreads();

    int wave = tid >> 6;
    int lane = tid & 63;
    int m = lane & 15, q = lane >> 4;
    int r0 = blockIdx.x * 64 + wave * 16;
    int ra = min(r0 + m, NN - 1);

    constexpr int NT = F / 16;
    f32x4 acc[NT];
    #pragma unroll
    for (int t = 0; t < NT; ++t) acc[t] = (f32x4){0.f, 0.f, 0.f, 0.f};

    #pragma unroll
    for (int c = 0; c < 4; ++c) {            // K = 128 = 4 x 32
        f16x8 a;
        if (AFP32) {
            const float* Af = (const float*)Ain;
            const float4* p = (const float4*)&Af[(size_t)ra * 128 + c * 32 + q * 8];
            float4 lo = p[0], hi = p[1];
            a[0] = (f16)lo.x; a[1] = (f16)lo.y; a[2] = (f16)lo.z; a[3] = (f16)lo.w;
            a[4] = (f16)hi.x; a[5] = (f16)hi.y; a[6] = (f16)hi.z; a[7] = (f16)hi.w;
        } else {
            const f16* Ah = (const f16*)Ain;
            a = *(const f16x8*)&Ah[(size_t)ra * 128 + c * 32 + q * 8];
        }
        #pragma unroll
        for (int t = 0; t < NT; ++t) {
            f16x8 b = *(const f16x8*)&Wt[(t * 16 + m) * PITCH + c * 32 + q * 8];
            acc[t] = __builtin_amdgcn_mfma_f32_16x16x32_f16(a, b, acc[t], 0, 0, 0);
        }
    }

    int rows[4];
    float dv[4];
    #pragma unroll
    for (int i = 0; i < 4; ++i) {
        rows[i] = r0 + q * 4 + i;
        dv[i] = dinv[min(rows[i], NN - 1)];
    }
    #pragma unroll
    for (int t = 0; t < NT; ++t) {
        #pragma unroll
        for (int i = 0; i < 4; ++i) {
            if (rows[i] < NN) {
                T[(size_t)rows[i] * F + t * 16 + m] = (f16)(acc[t][i] * dv[i]);
            }
        }
    }
}

// ---------------- SpMM gather, 2 rows per thread for 2x memory-level parallelism ----------------
// out[r] = dinv[r]*(sum_{c in nbr} T'[c] + T'[r]) + b ; T' dinv-prescaled.
// Each thread owns rows rA (rs) and rB (rs+RPB); both edge streams x4-unrolled
// and interleaved -> up to 8 independent 16B gathers in flight.
template<int F, bool RELU, bool OUTF16>
__global__ __launch_bounds__(256) void spmm_h2(const f16* __restrict__ T,
                                               const int* __restrict__ offsets,
                                               const int* __restrict__ csr_col,
                                               const float* __restrict__ dinv,
                                               const float* __restrict__ bias,
                                               void* __restrict__ outv) {
    constexpr int LPR = F / 8;          // lanes per row: 16 (F=128) or 8 (F=64)
    constexpr int RPB = 256 / LPR;      // rows per half-block: 16 or 32
    int lane = threadIdx.x % LPR;
    int rs   = threadIdx.x / LPR;
    int rA   = blockIdx.x * (2 * RPB) + rs;
    int rB   = rA + RPB;
    bool hasA = rA < NN, hasB = rB < NN;
    if (!hasA) return;                   // rB > rA, so also absent

    const f16x8* Tv = (const f16x8*)T;

    int a0 = offsets[rA], a1 = offsets[rA + 1];
    int b0 = 0, b1 = 0;
    if (hasB) { b0 = offsets[rB]; b1 = offsets[rB + 1]; }

    float sA0[8], sA1[8], sB0[8], sB1[8];
    f16x8 selfA = Tv[(size_t)rA * LPR + lane];
    #pragma unroll
    for (int u = 0; u < 8; ++u) { sA0[u] = (float)selfA[u]; sA1[u] = 0.f; sB0[u] = 0.f; sB1[u] = 0.f; }
    if (hasB) {
        f16x8 selfB = Tv[(size_t)rB * LPR + lane];
        #pragma unroll
        for (int u = 0; u < 8; ++u) sB0[u] = (float)selfB[u];
    }

    int jA = a0, jB = b0;
    // phase 1: both rows stream x4 chunks together (8 gathers in flight)
    while (jA + 4 <= a1 && jB + 4 <= b1) {
        int cA0 = csr_col[jA], cA1 = csr_col[jA + 1], cA2 = csr_col[jA + 2], cA3 = csr_col[jA + 3];
        int cB0 = csr_col[jB], cB1 = csr_col[jB + 1], cB2 = csr_col[jB + 2], cB3 = csr_col[jB + 3];
        f16x8 vA0 = Tv[(size_t)cA0 * LPR + lane];
        f16x8 vA1 = Tv[(size_t)cA1 * LPR + lane];
        f16x8 vA2 = Tv[(size_t)cA2 * LPR + lane];
        f16x8 vA3 = Tv[(size_t)cA3 * LPR + lane];
        f16x8 vB0 = Tv[(size_t)cB0 * LPR + lane];
        f16x8 vB1 = Tv[(size_t)cB1 * LPR + lane];
        f16x8 vB2 = Tv[(size_t)cB2 * LPR + lane];
        f16x8 vB3 = Tv[(size_t)cB3 * LPR + lane];
        #pragma unroll
        for (int u = 0; u < 8; ++u) {
            sA0[u] += (float)vA0[u] + (float)vA1[u];
            sA1[u] += (float)vA2[u] + (float)vA3[u];
            sB0[u] += (float)vB0[u] + (float)vB1[u];
            sB1[u] += (float)vB2[u] + (float)vB3[u];
        }
        jA += 4; jB += 4;
    }
    // phase 2: drain whichever row still has x4 chunks
    for (; jA + 4 <= a1; jA += 4) {
        int c0 = csr_col[jA], c1 = csr_col[jA + 1], c2 = csr_col[jA + 2], c3 = csr_col[jA + 3];
        f16x8 v0 = Tv[(size_t)c0 * LPR + lane];
        f16x8 v1 = Tv[(size_t)c1 * LPR + lane];
        f16x8 v2 = Tv[(size_t)c2 * LPR + lane];
        f16x8 v3 = Tv[(size_t)c3 * LPR + lane];
        #pragma unroll
        for (int u = 0; u < 8; ++u) {
            sA0[u] += (float)v0[u] + (float)v1[u];
            sA1[u] += (float)v2[u] + (float)v3[u];
        }
    }
    for (; jB + 4 <= b1; jB += 4) {
        int c0 = csr_col[jB], c1 = csr_col[jB + 1], c2 = csr_col[jB + 2], c3 = csr_col[jB + 3];
        f16x8 v0 = Tv[(size_t)c0 * LPR + lane];
        f16x8 v1 = Tv[(size_t)c1 * LPR + lane];
        f16x8 v2 = Tv[(size_t)c2 * LPR + lane];
        f16x8 v3 = Tv[(size_t)c3 * LPR + lane];
        #pragma unroll
        for (int u = 0; u < 8; ++u) {
            sB0[u] += (float)v0[u] + (float)v1[u];
            sB1[u] += (float)v2[u] + (float)v3[u];
        }
    }
    // phase 3: remainders (<4 each)
    for (; jA < a1; ++jA) {
        f16x8 v = Tv[(size_t)csr_col[jA] * LPR + lane];
        #pragma unroll
        for (int u = 0; u < 8; ++u) sA0[u] += (float)v[u];
    }
    for (; jB < b1; ++jB) {
        f16x8 v = Tv[(size_t)csr_col[jB] * LPR + lane];
        #pragma unroll
        for (int u = 0; u < 8; ++u) sB0[u] += (float)v[u];
    }

    float biasv[8];
    #pragma unroll
    for (int u = 0; u < 8; ++u) biasv[u] = bias[lane * 8 + u];

    // epilogue row A
    {
        float dr = dinv[rA];
        float o[8];
        #pragma unroll
        for (int u = 0; u < 8; ++u) {
            o[u] = fmaf(dr, sA0[u] + sA1[u], biasv[u]);
            if (RELU) o[u] = fmaxf(o[u], 0.f);
        }
        if (OUTF16) {
            f16x8 h;
            #pragma unroll
            for (int u = 0; u < 8; ++u) h[u] = (f16)o[u];
            ((f16x8*)outv)[(size_t)rA * LPR + lane] = h;
        } else {
            float* outF = (float*)outv;
            *(float4*)&outF[(size_t)rA * F + lane * 8]     = make_float4(o[0], o[1], o[2], o[3]);
            *(float4*)&outF[(size_t)rA * F + lane * 8 + 4] = make_float4(o[4], o[5], o[6], o[7]);
        }
    }
    // epilogue row B
    if (hasB) {
        float dr = dinv[rB];
        float o[8];
        #pragma unroll
        for (int u = 0; u < 8; ++u) {
            o[u] = fmaf(dr, sB0[u] + sB1[u], biasv[u]);
            if (RELU) o[u] = fmaxf(o[u], 0.f);
        }
        if (OUTF16) {
            f16x8 h;
            #pragma unroll
            for (int u = 0; u < 8; ++u) h[u] = (f16)o[u];
            ((f16x8*)outv)[(size_t)rB * LPR + lane] = h;
        } else {
            float* outF = (float*)outv;
            *(float4*)&outF[(size_t)rB * F + lane * 8]     = make_float4(o[0], o[1], o[2], o[3]);
            *(float4*)&outF[(size_t)rB * F + lane * 8 + 4] = make_float4(o[4], o[5], o[6], o[7]);
        }
    }
}

// ---------------- launch ----------------

extern "C" void kernel_launch(void* const* d_in, const int* in_sizes, int n_in,
                              void* d_out, int out_size, void* d_ws, size_t ws_size,
                              hipStream_t stream) {
    const float* x  = (const float*)d_in[0];
    const int*   ei = (const int*)d_in[1];
    const float* W0 = (const float*)d_in[2];
    const float* b0 = (const float*)d_in[3];
    const float* W1 = (const float*)d_in[4];
    const float* b1 = (const float*)d_in[5];
    const float* W2 = (const float*)d_in[6];
    const float* b2 = (const float*)d_in[7];
    float* out = (float*)d_out;

    const int* row = ei;
    const int* col = ei + NE;

    char* wsp = (char*)d_ws;
    auto alloc = [&](size_t bytes) {
        char* p = wsp;
        wsp += (bytes + 255) & ~(size_t)255;
        return p;
    };
    int*   bcursor = (int*)alloc((size_t)BK * 4);
    int2*  binned  = (int2*)alloc((size_t)BK * CAP * 8);   // 14.5 MB
    int*   offsets = (int*)alloc((size_t)(NN + 1) * 4);
    float* dinv    = (float*)alloc((size_t)NN * 4);
    int*   csr_col = (int*)alloc((size_t)NE * 4);
    f16*   Tbuf    = (f16*)alloc((size_t)NN * 128 * 2);
    f16*   Hbuf    = (f16*)alloc((size_t)NN * 128 * 2);

    // adjacency build: bin -> per-bucket LDS CSR
    zero_i32<<<1, 256, 0, stream>>>(bcursor, BK);
    bin_edges<<<(NE + CHUNK - 1) / CHUNK, 256, 0, stream>>>(row, col, bcursor, binned);
    build_csr<<<BK, 1024, 0, stream>>>(bcursor, binned, offsets, dinv, csr_col);

    const int GB = (NN + 63) / 64;

    // layer 1
    gemm_mfma<128, true><<<GB, 256, 0, stream>>>(x, W0, dinv, Tbuf);
    spmm_h2<128, true, true><<<(NN + 31) / 32, 256, 0, stream>>>(Tbuf, offsets, csr_col, dinv, b0, Hbuf);
    // layer 2
    gemm_mfma<128, false><<<GB, 256, 0, stream>>>(Hbuf, W1, dinv, Tbuf);
    spmm_h2<128, true, true><<<(NN + 31) / 32, 256, 0, stream>>>(Tbuf, offsets, csr_col, dinv, b1, Hbuf);
    // layer 3 (no relu) -> fp32 d_out
    gemm_mfma<64, false><<<GB, 256, 0, stream>>>(Hbuf, W2, dinv, Tbuf);
    spmm_h2<64, false, false><<<(NN + 63) / 64, 256, 0, stream>>>(Tbuf, offsets, csr_col, dinv, b2, out);
}